// Round 3
// baseline (304.040 us; speedup 1.0000x reference)
//
#include <hip/hip_runtime.h>
#include <cstdint>

// Problem: B=8, LQ=LK=2048, DIM=128.
// out  [B,LQ,DIM] f32 = softmax(mask? -inf : QK^T/sqrt(D)) @ K
// attn [B,LQ,LK]  f32 = log_softmax(...)  (clamp logp to -1e30)
//
// R7 == R6 resubmit (R6 never ran: container infra failure; source audited
//     for faults — bounds/alignment/barrier-uniformity/dbuf races all clean).
// R6: R4/R5 both hit ~105us with all pipes <25% -> shared L2/memory-system
//     ceiling (each 16-row block re-read full 1MB K+V; ~1.5GB L2 chip-wide).
//     This version: 64 q-rows per block (8 waves = 2 qgroups x 4 k-parities),
//     K/V staged once per block into double-buffered LDS (T14 reg-staging:
//     issue loads early, ds_write after compute). 4x fewer L2 reads.
//     32 rows/wave halves LDS reads per S-elem (frag feeds 2 sub-blocks).
//     1/sqrt(D) folded into Q at prep. Grid 256 = 1 block/CU.

#define DIMV 128
constexpr int BB = 8;
constexpr int LQ = 2048;
constexpr int LK = 2048;
constexpr float QSCALE = 0.08838834764831843f; // 1/sqrt(128), folded into Q

typedef _Float16 half8 __attribute__((ext_vector_type(8)));
typedef _Float16 half4v __attribute__((ext_vector_type(4)));
typedef float float4v __attribute__((ext_vector_type(4)));

// ---- prep: build fragment-major Qf, Kf, Vf (fp16) in ws ----
// Qf/Kf[b]: [tile(128)][kk(4)][lane(64)][8]  elem [t*16+l16][kk*32+quad*8+e]
// Vf[b]:    [kt(128)][dp(4)][lane(64)][8]    elem e<4:  V[kt*16+quad*4+e][(2dp)*16+l16]
//                                            elem e>=4: V[kt*16+quad*4+e-4][(2dp+1)*16+l16]
__global__ __launch_bounds__(256) void prep_kernel(const float* __restrict__ q,
                                                   const float* __restrict__ ctx,
                                                   _Float16* __restrict__ Qf,
                                                   _Float16* __restrict__ Kf,
                                                   _Float16* __restrict__ Vf) {
    __shared__ float tile[32][132];
    const int tid  = threadIdx.x;
    const int mode = blockIdx.x >> 9;     // 0:Qf 1:Kf 2:Vf
    const int t    = blockIdx.x & 511;
    const int b    = t >> 6;
    const int r0   = (t & 63) * 32;       // 32 rows of 2048
    const float4* s4 = (const float4*)((mode == 0 ? q : ctx) + ((size_t)b * 2048 + r0) * DIMV);
    for (int v = 0; v < 4; v++) {
        int off = tid + v * 256;
        float4 f = s4[off];
        int row = off >> 5, c4 = (off & 31) * 4;
        tile[row][c4 + 0] = f.x; tile[row][c4 + 1] = f.y;
        tile[row][c4 + 2] = f.z; tile[row][c4 + 3] = f.w;
    }
    __syncthreads();
    if (mode < 2) {
        const float qs = (mode == 0) ? QSCALE : 1.0f;
        _Float16* dst = (mode == 0 ? Qf : Kf) + (size_t)b * (2048 * DIMV);
        for (int c = 0; c < 2; c++) {
            int chunk = tid + c * 256;                 // (t2, kk, lane)
            int t2 = chunk >> 8, kk = (chunk >> 6) & 3, lane = chunk & 63;
            int quad = lane >> 4, l16 = lane & 15;
            int r = t2 * 16 + l16, d0 = kk * 32 + quad * 8;
            half8 h;
            for (int e = 0; e < 8; e++) h[e] = (_Float16)(tile[r][d0 + e] * qs);
            size_t tl = (size_t)(r0 >> 4) + t2;
            *(half8*)(dst + ((tl * 4 + kk) * 64 + lane) * 8) = h;
        }
    } else {
        _Float16* dst = Vf + (size_t)b * (2048 * DIMV);
        const int kt0 = r0 >> 4;
        for (int c = 0; c < 2; c++) {
            int chunk = tid + c * 256;                 // (ktl, dp, lane)
            int ktl = chunk >> 8, dp = (chunk >> 6) & 3, ln = chunk & 63;
            int qd = ln >> 4, s16 = ln & 15;
            half8 h;
            for (int e = 0; e < 4; e++) {
                h[e]     = (_Float16)tile[ktl * 16 + qd * 4 + e][(2 * dp) * 16 + s16];
                h[e + 4] = (_Float16)tile[ktl * 16 + qd * 4 + e][(2 * dp + 1) * 16 + s16];
            }
            *(half8*)(dst + ((((size_t)(kt0 + ktl)) * 4 + dp) * 64 + ln) * 8) = h;
        }
    }
}

// ---- main fused kernel: one block = (batch, 64 q-rows), 8 waves, 1 blk/CU ----
// wave = qg(2 groups of 32 rows, 2 MFMA sub-blocks) x parity p(4): k-tiles 4i+p.
__global__ __launch_bounds__(512, 1)
void attn_kernel(const unsigned char* __restrict__ mask,
                 const _Float16* __restrict__ Qf, const _Float16* __restrict__ Kf,
                 const _Float16* __restrict__ Vf,
                 float* __restrict__ out, float* __restrict__ out_attn) {
    // STG[buf]: halfs [ K tiles 0..3 @ t*2048 | V tiles 0..3 @ 8192 + t*2048 ]
    __shared__ __attribute__((aligned(16))) _Float16 STG[2][16384]; // 64 KB
    __shared__ __attribute__((aligned(16))) float pvsum[64][132];   // 33.8 KB
    __shared__ float redm[8][32], redl[8][32], swf[8][32];
    __shared__ float mcl64[64], rls64[64];

    const int tid  = threadIdx.x;
    const int wave = tid >> 6;
    const int lane = tid & 63;
    const int l16  = lane & 15;
    const int quad = lane >> 4;
    const int p    = wave & 3;   // k-parity
    const int qg   = wave >> 2;  // q-group (32 rows)

    const int b   = blockIdx.x & 7;       // XCD-aware batch mapping
    const int qt4 = blockIdx.x >> 3;      // 0..31
    const int q0  = qt4 * 64;

    const _Float16* Qb = Qf + (size_t)b * (2048 * DIMV);
    const _Float16* Kb = Kf + (size_t)b * (2048 * DIMV);
    const _Float16* Vb = Vf + (size_t)b * (2048 * DIMV);

    // Q fragments (B-operand), pre-scaled by 1/sqrt(D): 2 sub-blocks of 16 rows
    half8 qfrag[2][4];
#pragma unroll
    for (int sub = 0; sub < 2; sub++) {
        const size_t tq = (size_t)qt4 * 4 + qg * 2 + sub;
#pragma unroll
        for (int kk = 0; kk < 4; kk++)
            qfrag[sub][kk] = *(const half8*)(Qb + ((tq * 4 + kk) * 64 + lane) * 8);
    }

    // mask base: row q0+qg*32+l16 (sub adds 16 rows), col p*16+quad*4 (iter adds i*64)
    const unsigned char* mrow0 = mask + ((size_t)b * LQ + q0 + qg * 32 + l16) * LK + p * 16 + quad * 4;

    const float NEGINF = -__builtin_inff();
    float m0r = -1e30f, m1r = -1e30f;   // finite sentinel (avoid inf-inf NaN)
    float l0r = 0.f, l1r = 0.f;
    float4v oacc[2][8];
#pragma unroll
    for (int sub = 0; sub < 2; sub++)
#pragma unroll
        for (int dt = 0; dt < 8; dt++) oacc[sub][dt] = (float4v){0.f, 0.f, 0.f, 0.f};

    // --- pass-1 staging: waves 0-3 stage K tile (wave&3), waves 4-7 stage V tile ---
    const _Float16* gsb = (wave < 4) ? Kb : Vb;
    const int wt = wave & 3;
    const unsigned dsto = ((wave < 4) ? 0u : 8192u) + (unsigned)wt * 2048;

    {   // prologue: supertile 0 -> buf 0
        const _Float16* src = gsb + (size_t)(0 * 4 + wt) * 2048 + lane * 8;
        float4 r4[4];
#pragma unroll
        for (int c = 0; c < 4; c++) r4[c] = *(const float4*)(src + c * 512);
        _Float16* d = &STG[0][dsto];
#pragma unroll
        for (int c = 0; c < 4; c++) *(float4*)(d + c * 512 + lane * 8) = r4[c];
    }
    __syncthreads();

    // ---- pass 1: 32 supertiles of 64 cols; this wave computes tile 4i+p ----
    for (int i = 0; i < 32; ++i) {
        const int cur = i & 1, nxt = cur ^ 1;
        const bool more = (i + 1 < 32);
        float4 nr4[4];
        if (more) {                       // T14: issue next-supertile loads early
            const _Float16* src = gsb + (size_t)(4 * (i + 1) + wt) * 2048 + lane * 8;
#pragma unroll
            for (int c = 0; c < 4; c++) nr4[c] = *(const float4*)(src + c * 512);
        }

        const _Float16* kt = &STG[cur][p * 2048];
        const _Float16* vt = &STG[cur][8192 + p * 2048];
        half8 kf[4], vv[4];
#pragma unroll
        for (int kk = 0; kk < 4; kk++) kf[kk] = *(const half8*)(kt + kk * 512 + lane * 8);
#pragma unroll
        for (int dp = 0; dp < 4; dp++) vv[dp] = *(const half8*)(vt + dp * 512 + lane * 8);

#pragma unroll
        for (int sub = 0; sub < 2; sub++) {
            float4v st = (float4v){0.f, 0.f, 0.f, 0.f};
#pragma unroll
            for (int kk = 0; kk < 4; kk++)
                st = __builtin_amdgcn_mfma_f32_16x16x32_f16(kf[kk], qfrag[sub][kk], st, 0, 0, 0);
            const uint32_t mv = *(const uint32_t*)(mrow0 + (size_t)sub * 16 * LK + (size_t)i * 64);
            float& m = sub ? m1r : m0r;
            float& l = sub ? l1r : l0r;
            float sv[4];
#pragma unroll
            for (int r = 0; r < 4; r++) {
                float v = st[r];
                if ((mv >> (8 * r)) & 0xffu) v = NEGINF;
                sv[r] = v;
            }
            float tmax = fmaxf(fmaxf(sv[0], sv[1]), fmaxf(sv[2], sv[3]));
            tmax = fmaxf(tmax, __shfl_xor(tmax, 16));
            tmax = fmaxf(tmax, __shfl_xor(tmax, 32));
            const bool upd = tmax > m + 3.0f;   // defer-rescale: p bounded by e^3
            if (__any(upd)) {
                const float mnew = upd ? tmax : m;
                const float sc = __expf(m - mnew);
                float scr[4];
#pragma unroll
                for (int r = 0; r < 4; r++) scr[r] = __shfl(sc, quad * 4 + r);
                l *= sc;
#pragma unroll
                for (int dt = 0; dt < 8; dt++)
#pragma unroll
                    for (int r = 0; r < 4; r++) oacc[sub][dt][r] *= scr[r];
                m = mnew;
            }
            half4v pa;
            float psum = 0.f;
#pragma unroll
            for (int r = 0; r < 4; r++) {
                const float pp = __expf(sv[r] - m);   // masked: exp(-inf)=0
                psum += pp;
                pa[r] = (_Float16)pp;
            }
            psum += __shfl_xor(psum, 16);
            psum += __shfl_xor(psum, 32);
            l += psum;
#pragma unroll
            for (int dp = 0; dp < 4; dp++) {
                half4v vlo = __builtin_shufflevector(vv[dp], vv[dp], 0, 1, 2, 3);
                half4v vhi = __builtin_shufflevector(vv[dp], vv[dp], 4, 5, 6, 7);
                oacc[sub][2 * dp]     = __builtin_amdgcn_mfma_f32_16x16x16f16(pa, vlo, oacc[sub][2 * dp],     0, 0, 0);
                oacc[sub][2 * dp + 1] = __builtin_amdgcn_mfma_f32_16x16x16f16(pa, vhi, oacc[sub][2 * dp + 1], 0, 0, 0);
            }
        }

        if (more) {                       // write-late: vmcnt latency covered by compute
            _Float16* d = &STG[nxt][dsto];
#pragma unroll
            for (int c = 0; c < 4; c++) *(float4*)(d + c * 512 + lane * 8) = nr4[c];
        }
        __syncthreads();
    }

    // ---- merge stats across 4 parities ----
    if (quad == 0) {
        redm[wave][l16]      = m0r;  redm[wave][16 + l16] = m1r;
        redl[wave][l16]      = l0r;  redl[wave][16 + l16] = l1r;
    }
    // pass-2 pre-stage issue (supertile 0, K only), hidden under the merge
    float4 pre2[2];
    {
        const int t0 = wave >> 2, kkw = wave & 3;
        pre2[0] = *(const float4*)(Kb + (size_t)(t0)     * 2048 + kkw * 512 + lane * 8);
        pre2[1] = *(const float4*)(Kb + (size_t)(t0 + 2) * 2048 + kkw * 512 + lane * 8);
    }
    __syncthreads();
    if (tid < 64) {
        const int qg2 = tid >> 5, r32 = tid & 31;
        float mm[4], ll[4];
#pragma unroll
        for (int pp = 0; pp < 4; pp++) { mm[pp] = redm[qg2 * 4 + pp][r32]; ll[pp] = redl[qg2 * 4 + pp][r32]; }
        const float M = fmaxf(fmaxf(mm[0], mm[1]), fmaxf(mm[2], mm[3]));
        float L = 0.f;
#pragma unroll
        for (int pp = 0; pp < 4; pp++) {
            const float e = __expf(mm[pp] - M);
            swf[qg2 * 4 + pp][r32] = e;
            L += e * ll[pp];
        }
        mcl64[tid] = M + __logf(L);
        rls64[tid] = 1.0f / L;
    }
    __syncthreads();

    // ---- PV merge: 4 rounds of LDS RMW (parity rnd adds its scaled partials) ----
    for (int rnd = 0; rnd < 4; ++rnd) {
        if (p == rnd) {
#pragma unroll
            for (int sub = 0; sub < 2; sub++)
#pragma unroll
                for (int r = 0; r < 4; r++) {
                    const int row = qg * 32 + sub * 16 + quad * 4 + r;
                    const float sc = swf[wave][sub * 16 + quad * 4 + r];
#pragma unroll
                    for (int dt = 0; dt < 8; dt++) {
                        const float v = oacc[sub][dt][r] * sc;
                        if (rnd == 0) pvsum[row][dt * 16 + l16] = v;
                        else          pvsum[row][dt * 16 + l16] += v;
                    }
                }
        }
        __syncthreads();
    }

    // ---- out = pvsum / L, coalesced float4 ----
    {
        const int row = tid >> 3;
        const int c0  = (tid & 7) * 16;
        const float rcl = rls64[row];
        float* op = out + ((size_t)b * LQ + q0 + row) * DIMV + c0;
#pragma unroll
        for (int h = 0; h < 4; h++) {
            float4v a = *(const float4v*)&pvsum[row][c0 + h * 4];
            float4v v;
#pragma unroll
            for (int j = 0; j < 4; j++) v[j] = a[j] * rcl;
            *(float4v*)(op + h * 4) = v;
        }
    }

    // stage pre2 -> STG[0] (K tiles of supertile 0) and sync
    {
        const int t0 = wave >> 2, kkw = wave & 3;
        *(float4*)(&STG[0][(t0)     * 2048 + kkw * 512] + lane * 8) = pre2[0];
        *(float4*)(&STG[0][(t0 + 2) * 2048 + kkw * 512] + lane * 8) = pre2[1];
    }
    __syncthreads();

    // ---- pass 2: recompute QK^T from LDS-staged K, write logp ----
    const float mc0 = mcl64[qg * 32 + l16];
    const float mc1 = mcl64[qg * 32 + 16 + l16];
    float* oa0 = out_attn + ((size_t)b * LQ + q0 + qg * 32 + l16) * LK + p * 16 + quad * 4;
    for (int i = 0; i < 32; ++i) {
        const int cur = i & 1, nxt = cur ^ 1;
        const bool more = (i + 1 < 32);
        float4 n2[2];
        if (more) {
            const int t0 = wave >> 2, kkw = wave & 3;
            n2[0] = *(const float4*)(Kb + (size_t)(4 * (i + 1) + t0)     * 2048 + kkw * 512 + lane * 8);
            n2[1] = *(const float4*)(Kb + (size_t)(4 * (i + 1) + t0 + 2) * 2048 + kkw * 512 + lane * 8);
        }
        const _Float16* kt = &STG[cur][p * 2048];
        half8 kf[4];
#pragma unroll
        for (int kk = 0; kk < 4; kk++) kf[kk] = *(const half8*)(kt + kk * 512 + lane * 8);
#pragma unroll
        for (int sub = 0; sub < 2; sub++) {
            float4v st = (float4v){0.f, 0.f, 0.f, 0.f};
#pragma unroll
            for (int kk = 0; kk < 4; kk++)
                st = __builtin_amdgcn_mfma_f32_16x16x32_f16(kf[kk], qfrag[sub][kk], st, 0, 0, 0);
            const uint32_t mv = *(const uint32_t*)(mrow0 + (size_t)sub * 16 * LK + (size_t)i * 64);
            const float mc = sub ? mc1 : mc0;
            float4v o;
#pragma unroll
            for (int r = 0; r < 4; r++) {
                float lp = st[r] - mc;
                if ((mv >> (8 * r)) & 0xffu) lp = -1.0e30f;   // masked: finite sentinel
                o[r] = fmaxf(lp, -1.0e30f);
            }
            *(float4v*)(oa0 + (size_t)sub * 16 * LK + (size_t)i * 64) = o;
        }
        if (more) {
            const int t0 = wave >> 2, kkw = wave & 3;
            *(float4*)(&STG[nxt][(t0)     * 2048 + kkw * 512] + lane * 8) = n2[0];
            *(float4*)(&STG[nxt][(t0 + 2) * 2048 + kkw * 512] + lane * 8) = n2[1];
        }
        __syncthreads();
    }
}

extern "C" void kernel_launch(void* const* d_in, const int* in_sizes, int n_in,
                              void* d_out, int out_size, void* d_ws, size_t ws_size,
                              hipStream_t stream) {
    const float* q_f32 = (const float*)d_in[0];
    const float* c_f32 = (const float*)d_in[1];
    const unsigned char* mask = (const unsigned char*)d_in[2];

    float* out      = (float*)d_out;
    float* out_attn = out + (size_t)BB * LQ * DIMV;

    _Float16* Qf = (_Float16*)d_ws;                    // 4.19 MB each
    _Float16* Kf = Qf + (size_t)BB * LQ * DIMV;
    _Float16* Vf = Kf + (size_t)BB * LK * DIMV;

    prep_kernel<<<1536, 256, 0, stream>>>(q_f32, c_f32, Qf, Kf, Vf);
    attn_kernel<<<BB * (LQ / 64), 512, 0, stream>>>(mask, Qf, Kf, Vf, out, out_attn);
}

// Round 4
// 277.101 us; speedup vs baseline: 1.0972x; 1.0972x over previous
//
#include <hip/hip_runtime.h>
#include <cstdint>

// Problem: B=8, LQ=LK=2048, DIM=128.
// out  [B,LQ,DIM] f32 = softmax(mask? -inf : QK^T/sqrt(D)) @ K
// attn [B,LQ,LK]  f32 = log_softmax(...)  (clamp logp to -1e30)
//
// R8: R4/R5/R7 all ~101-114us, every pipe <25% -> exposed load latency on the
//     serial per-tile chain (VGPR 52-88 shows compiler kept nothing in flight;
//     R7's per-iter barrier vmcnt(0)-drained its prefetch).
//     Fix: barrier-free main loops + explicit 2-buffer REGISTER prefetch of
//     K-frags/V-frags/mask one tile ahead (issue-early, consume-next-iter),
//     sched_barrier(0) pin, unroll-2 for static buffer indices, setprio
//     around MFMA clusters, psum reduce moved off the critical path.
//     4-wave/32-row blocks, wave owns 512-col strip, grid 512 = 2 blk/CU.

#define DIMV 128
constexpr int BB = 8;
constexpr int LQ = 2048;
constexpr int LK = 2048;
constexpr float QSCALE = 0.08838834764831843f; // 1/sqrt(128), folded into Q

typedef _Float16 half8 __attribute__((ext_vector_type(8)));
typedef _Float16 half4v __attribute__((ext_vector_type(4)));
typedef float float4v __attribute__((ext_vector_type(4)));

// ---- prep: build fragment-major Qf, Kf, Vf (fp16) in ws ---- (verified R7)
// Qf/Kf[b]: [tile(128)][kk(4)][lane(64)][8]  elem [t*16+l16][kk*32+quad*8+e]
// Vf[b]:    [kt(128)][dp(4)][lane(64)][8]    elem e<4:  V[kt*16+quad*4+e][(2dp)*16+l16]
//                                            elem e>=4: V[kt*16+quad*4+e-4][(2dp+1)*16+l16]
__global__ __launch_bounds__(256) void prep_kernel(const float* __restrict__ q,
                                                   const float* __restrict__ ctx,
                                                   _Float16* __restrict__ Qf,
                                                   _Float16* __restrict__ Kf,
                                                   _Float16* __restrict__ Vf) {
    __shared__ float tile[32][132];
    const int tid  = threadIdx.x;
    const int mode = blockIdx.x >> 9;     // 0:Qf 1:Kf 2:Vf
    const int t    = blockIdx.x & 511;
    const int b    = t >> 6;
    const int r0   = (t & 63) * 32;       // 32 rows of 2048
    const float4* s4 = (const float4*)((mode == 0 ? q : ctx) + ((size_t)b * 2048 + r0) * DIMV);
    for (int v = 0; v < 4; v++) {
        int off = tid + v * 256;
        float4 f = s4[off];
        int row = off >> 5, c4 = (off & 31) * 4;
        tile[row][c4 + 0] = f.x; tile[row][c4 + 1] = f.y;
        tile[row][c4 + 2] = f.z; tile[row][c4 + 3] = f.w;
    }
    __syncthreads();
    if (mode < 2) {
        const float qs = (mode == 0) ? QSCALE : 1.0f;
        _Float16* dst = (mode == 0 ? Qf : Kf) + (size_t)b * (2048 * DIMV);
        for (int c = 0; c < 2; c++) {
            int chunk = tid + c * 256;                 // (t2, kk, lane)
            int t2 = chunk >> 8, kk = (chunk >> 6) & 3, lane = chunk & 63;
            int quad = lane >> 4, l16 = lane & 15;
            int r = t2 * 16 + l16, d0 = kk * 32 + quad * 8;
            half8 h;
            for (int e = 0; e < 8; e++) h[e] = (_Float16)(tile[r][d0 + e] * qs);
            size_t tl = (size_t)(r0 >> 4) + t2;
            *(half8*)(dst + ((tl * 4 + kk) * 64 + lane) * 8) = h;
        }
    } else {
        _Float16* dst = Vf + (size_t)b * (2048 * DIMV);
        const int kt0 = r0 >> 4;
        for (int c = 0; c < 2; c++) {
            int chunk = tid + c * 256;                 // (ktl, dp, lane)
            int ktl = chunk >> 8, dp = (chunk >> 6) & 3, ln = chunk & 63;
            int qd = ln >> 4, s16 = ln & 15;
            half8 h;
            for (int e = 0; e < 4; e++) {
                h[e]     = (_Float16)tile[ktl * 16 + qd * 4 + e][(2 * dp) * 16 + s16];
                h[e + 4] = (_Float16)tile[ktl * 16 + qd * 4 + e][(2 * dp + 1) * 16 + s16];
            }
            *(half8*)(dst + ((((size_t)(kt0 + ktl)) * 4 + dp) * 64 + ln) * 8) = h;
        }
    }
}

// ---- main fused kernel: one block = (batch, 32 q-rows), 4 waves, 2 blk/CU ----
// wave owns col-strip [wave*512, wave*512+512); 2 sub-blocks of 16 rows.
__global__ __launch_bounds__(256, 2)
void attn_kernel(const unsigned char* __restrict__ mask,
                 const _Float16* __restrict__ Qf, const _Float16* __restrict__ Kf,
                 const _Float16* __restrict__ Vf,
                 float* __restrict__ out, float* __restrict__ out_attn) {
    __shared__ __attribute__((aligned(16))) float pvsum[32][132];   // 16.9 KB
    __shared__ float redm[4][32], redl[4][32], swf[4][32];
    __shared__ float mcl32[32], rls32[32];

    const int tid  = threadIdx.x;
    const int wave = tid >> 6;
    const int lane = tid & 63;
    const int l16  = lane & 15;
    const int quad = lane >> 4;

    const int b  = blockIdx.x & 7;       // XCD-aware batch mapping (batch b -> XCD b)
    const int qg = blockIdx.x >> 3;      // 0..63
    const int q0 = qg * 32;

    const _Float16* Qb = Qf + (size_t)b * (2048 * DIMV);
    const _Float16* Kb = Kf + (size_t)b * (2048 * DIMV);
    const _Float16* Vb = Vf + (size_t)b * (2048 * DIMV);

    // Q fragments (B-operand), pre-scaled: 2 sub-blocks of 16 rows
    half8 qfrag[2][4];
#pragma unroll
    for (int sub = 0; sub < 2; sub++) {
        const size_t tq = (size_t)qg * 2 + sub;
#pragma unroll
        for (int kk = 0; kk < 4; kk++)
            qfrag[sub][kk] = *(const half8*)(Qb + ((tq * 4 + kk) * 64 + lane) * 8);
    }

    // mask base: row q0+l16 (sub adds 16 rows), col wave*512 + quad*4 (tile adds ct*16)
    const unsigned char* mrow0 = mask + ((size_t)b * LQ + q0 + l16) * LK + wave * 512 + quad * 4;

    const _Float16* kstrip = Kb + (size_t)wave * 32 * 2048; // this wave's 32 k-tiles
    const _Float16* vstrip = Vb + (size_t)wave * 32 * 2048;

    const float NEGINF = -__builtin_inff();
    float m0r = -1e30f, m1r = -1e30f;   // finite sentinel (avoid inf-inf NaN)
    float l0r = 0.f, l1r = 0.f;
    float4v oacc[2][8];
#pragma unroll
    for (int sub = 0; sub < 2; sub++)
#pragma unroll
        for (int dt = 0; dt < 8; dt++) oacc[sub][dt] = (float4v){0.f, 0.f, 0.f, 0.f};

    // ---- register double-buffer prefetch state ----
    half8 kfb[2][4], vvb[2][4];
    uint32_t mvb[2][2];
    {   // prologue: tile 0 -> buf 0
#pragma unroll
        for (int kk = 0; kk < 4; kk++) kfb[0][kk] = *(const half8*)(kstrip + (kk * 64 + lane) * 8);
#pragma unroll
        for (int dp = 0; dp < 4; dp++) vvb[0][dp] = *(const half8*)(vstrip + (dp * 64 + lane) * 8);
#pragma unroll
        for (int s = 0; s < 2; s++) mvb[0][s] = *(const uint32_t*)(mrow0 + (size_t)s * 16 * LK);
    }

    // ---- pass 1: 32 tiles of 16 cols, barrier-free, issue-ahead pipeline ----
#pragma unroll 2
    for (int ct = 0; ct < 32; ++ct) {
        const int cur = ct & 1, nxt = cur ^ 1;
        const int cn  = (ct + 1) & 31;           // ct=31 reloads tile 0 (harmless)
        {   // issue next-tile loads FIRST; one full iteration of latency slack
            const _Float16* kp = kstrip + (size_t)cn * 2048;
            const _Float16* vp = vstrip + (size_t)cn * 2048;
#pragma unroll
            for (int kk = 0; kk < 4; kk++) kfb[nxt][kk] = *(const half8*)(kp + (kk * 64 + lane) * 8);
#pragma unroll
            for (int dp = 0; dp < 4; dp++) vvb[nxt][dp] = *(const half8*)(vp + (dp * 64 + lane) * 8);
#pragma unroll
            for (int s = 0; s < 2; s++)
                mvb[nxt][s] = *(const uint32_t*)(mrow0 + (size_t)s * 16 * LK + cn * 16);
        }
        __builtin_amdgcn_sched_barrier(0);       // pin: loads stay at iteration top

#pragma unroll
        for (int sub = 0; sub < 2; sub++) {
            float4v st = (float4v){0.f, 0.f, 0.f, 0.f};
            __builtin_amdgcn_s_setprio(1);
#pragma unroll
            for (int kk = 0; kk < 4; kk++)
                st = __builtin_amdgcn_mfma_f32_16x16x32_f16(kfb[cur][kk], qfrag[sub][kk], st, 0, 0, 0);
            __builtin_amdgcn_s_setprio(0);
            const uint32_t mv = mvb[cur][sub];   // prefetched: no load on critical path
            float& m = sub ? m1r : m0r;
            float& l = sub ? l1r : l0r;
            float sv[4];
#pragma unroll
            for (int r = 0; r < 4; r++) {
                float v = st[r];
                if ((mv >> (8 * r)) & 0xffu) v = NEGINF;
                sv[r] = v;
            }
            float tmax = fmaxf(fmaxf(sv[0], sv[1]), fmaxf(sv[2], sv[3]));
            tmax = fmaxf(tmax, __shfl_xor(tmax, 16));
            tmax = fmaxf(tmax, __shfl_xor(tmax, 32));
            const bool upd = tmax > m + 3.0f;    // defer-rescale: p bounded by e^3
            if (__any(upd)) {
                const float mnew = upd ? tmax : m;
                const float sc = __expf(m - mnew);
                float scr[4];
#pragma unroll
                for (int r = 0; r < 4; r++) scr[r] = __shfl(sc, quad * 4 + r);
                l *= sc;
#pragma unroll
                for (int dt = 0; dt < 8; dt++)
#pragma unroll
                    for (int r = 0; r < 4; r++) oacc[sub][dt][r] *= scr[r];
                m = mnew;
            }
            half4v pa;
            float pp[4];
#pragma unroll
            for (int r = 0; r < 4; r++) {
                pp[r] = __expf(sv[r] - m);       // masked: exp(-inf)=0
                pa[r] = (_Float16)pp[r];
            }
            // PV first (pa is the 16x16x16 A-operand directly)
            __builtin_amdgcn_s_setprio(1);
#pragma unroll
            for (int dp = 0; dp < 4; dp++) {
                half4v vlo = __builtin_shufflevector(vvb[cur][dp], vvb[cur][dp], 0, 1, 2, 3);
                half4v vhi = __builtin_shufflevector(vvb[cur][dp], vvb[cur][dp], 4, 5, 6, 7);
                oacc[sub][2 * dp]     = __builtin_amdgcn_mfma_f32_16x16x16f16(pa, vlo, oacc[sub][2 * dp],     0, 0, 0);
                oacc[sub][2 * dp + 1] = __builtin_amdgcn_mfma_f32_16x16x16f16(pa, vhi, oacc[sub][2 * dp + 1], 0, 0, 0);
            }
            __builtin_amdgcn_s_setprio(0);
            // l-update off the critical path (feeds nothing until the merge)
            float psum = (pp[0] + pp[1]) + (pp[2] + pp[3]);
            psum += __shfl_xor(psum, 16);
            psum += __shfl_xor(psum, 32);
            l += psum;
        }
    }

    // ---- merge stats across 4 col-strips ----
    if (quad == 0) {
        redm[wave][l16]      = m0r;  redm[wave][16 + l16] = m1r;
        redl[wave][l16]      = l0r;  redl[wave][16 + l16] = l1r;
    }
    // pass-2 prologue loads issued here: latency hidden under the merge barriers
    half8 kf2[2][4];
    uint32_t mv2[2][2];
#pragma unroll
    for (int kk = 0; kk < 4; kk++) kf2[0][kk] = *(const half8*)(kstrip + (kk * 64 + lane) * 8);
#pragma unroll
    for (int s = 0; s < 2; s++) mv2[0][s] = *(const uint32_t*)(mrow0 + (size_t)s * 16 * LK);
    __syncthreads();
    if (tid < 32) {
        float mm[4], ll[4];
#pragma unroll
        for (int p = 0; p < 4; p++) { mm[p] = redm[p][tid]; ll[p] = redl[p][tid]; }
        const float M = fmaxf(fmaxf(mm[0], mm[1]), fmaxf(mm[2], mm[3]));
        float L = 0.f;
#pragma unroll
        for (int p = 0; p < 4; p++) {
            const float e = __expf(mm[p] - M);
            swf[p][tid] = e;
            L += e * ll[p];
        }
        mcl32[tid] = M + __logf(L);
        rls32[tid] = 1.0f / L;
    }
    __syncthreads();

    // ---- PV merge: 4 rounds of LDS RMW ----
    for (int rnd = 0; rnd < 4; ++rnd) {
        if (wave == rnd) {
#pragma unroll
            for (int sub = 0; sub < 2; sub++)
#pragma unroll
                for (int r = 0; r < 4; r++) {
                    const int row = sub * 16 + quad * 4 + r;
                    const float sc = swf[wave][row];
#pragma unroll
                    for (int dt = 0; dt < 8; dt++) {
                        const float v = oacc[sub][dt][r] * sc;
                        if (rnd == 0) pvsum[row][dt * 16 + l16] = v;
                        else          pvsum[row][dt * 16 + l16] += v;
                    }
                }
        }
        __syncthreads();
    }

    // ---- out = pvsum / L, coalesced float4 ----
    {
        const int row = tid >> 3;
        const int c0  = (tid & 7) * 16;
        const float rcl = rls32[row];
        float* op = out + ((size_t)b * LQ + q0 + row) * DIMV + c0;
#pragma unroll
        for (int h = 0; h < 4; h++) {
            float4v a = *(const float4v*)&pvsum[row][c0 + h * 4];
            float4v v;
#pragma unroll
            for (int j = 0; j < 4; j++) v[j] = a[j] * rcl;
            *(float4v*)(op + h * 4) = v;
        }
    }

    // ---- pass 2: recompute QK^T (K frags L2-hot), barrier-free, prefetched ----
    const float mc0 = mcl32[l16];
    const float mc1 = mcl32[16 + l16];
    float* oa0 = out_attn + ((size_t)b * LQ + q0 + l16) * LK + wave * 512 + quad * 4;
#pragma unroll 2
    for (int ct = 0; ct < 32; ++ct) {
        const int cur = ct & 1, nxt = cur ^ 1;
        const int cn  = (ct + 1) & 31;
        {
            const _Float16* kp = kstrip + (size_t)cn * 2048;
#pragma unroll
            for (int kk = 0; kk < 4; kk++) kf2[nxt][kk] = *(const half8*)(kp + (kk * 64 + lane) * 8);
#pragma unroll
            for (int s = 0; s < 2; s++)
                mv2[nxt][s] = *(const uint32_t*)(mrow0 + (size_t)s * 16 * LK + cn * 16);
        }
        __builtin_amdgcn_sched_barrier(0);

#pragma unroll
        for (int sub = 0; sub < 2; sub++) {
            float4v st = (float4v){0.f, 0.f, 0.f, 0.f};
            __builtin_amdgcn_s_setprio(1);
#pragma unroll
            for (int kk = 0; kk < 4; kk++)
                st = __builtin_amdgcn_mfma_f32_16x16x32_f16(kf2[cur][kk], qfrag[sub][kk], st, 0, 0, 0);
            __builtin_amdgcn_s_setprio(0);
            const uint32_t mv = mv2[cur][sub];
            const float mc = sub ? mc1 : mc0;
            float4v o;
#pragma unroll
            for (int r = 0; r < 4; r++) {
                float lp = st[r] - mc;
                if ((mv >> (8 * r)) & 0xffu) lp = -1.0e30f;   // masked: finite sentinel
                o[r] = fmaxf(lp, -1.0e30f);
            }
            *(float4v*)(oa0 + (size_t)sub * 16 * LK + ct * 16) = o;
        }
    }
}

extern "C" void kernel_launch(void* const* d_in, const int* in_sizes, int n_in,
                              void* d_out, int out_size, void* d_ws, size_t ws_size,
                              hipStream_t stream) {
    const float* q_f32 = (const float*)d_in[0];
    const float* c_f32 = (const float*)d_in[1];
    const unsigned char* mask = (const unsigned char*)d_in[2];

    float* out      = (float*)d_out;
    float* out_attn = out + (size_t)BB * LQ * DIMV;

    _Float16* Qf = (_Float16*)d_ws;                    // 4.19 MB each
    _Float16* Kf = Qf + (size_t)BB * LQ * DIMV;
    _Float16* Vf = Kf + (size_t)BB * LK * DIMV;

    prep_kernel<<<1536, 256, 0, stream>>>(q_f32, c_f32, Qf, Kf, Vf);
    attn_kernel<<<BB * (LQ / 32), 256, 0, stream>>>(mask, Qf, Kf, Vf, out, out_attn);
}